// Round 12
// baseline (135.539 us; speedup 1.0000x reference)
//
#include <hip/hip_runtime.h>
#include <hip/hip_bf16.h>
#include <math.h>

// DIAGNOSTIC ROUND. Pipeline = round-6 best (59.6 us) but K2 runs its full
// tile-walk 3x (opaque asm between reps; output = logf(total/3), still valid)
// and a pure linear-read kernel runs 5x into dead scratch. Both dispatches
// exceed the 75 us harness fills -> they surface in rocprof top-5 with real
// counters, ending 5 rounds of blind K2 theorizing. Decision rules in journal.

// ---------------------------------------------------------------------------
// K1: offs[s] = first edge index with key >= s, for s in [0, S]; offs[S] = E.
// ---------------------------------------------------------------------------
__global__ void seg_offsets_kernel(const int* __restrict__ keys,
                                   int* __restrict__ offs,
                                   int E, int S) {
    int t = blockIdx.x * blockDim.x + threadIdx.x;
    int i0 = t * 4;
    if (i0 >= E) return;

    int4 k4 = reinterpret_cast<const int4*>(keys)[t];
    int prev = (i0 == 0) ? -1 : keys[i0 - 1];

    int ks[4] = {k4.x, k4.y, k4.z, k4.w};
    #pragma unroll
    for (int j = 0; j < 4; ++j) {
        int k = ks[j];
        for (int s = prev + 1; s <= k; ++s) offs[s] = i0 + j;
        prev = k;
    }
    if (i0 + 4 == E) {
        for (int s = prev + 1; s <= S; ++s) offs[s] = E;
    }
}

// ---------------------------------------------------------------------------
// D1: round-6 K2 (LDS dbuf + register prefetch + b128 reduce), 3 reps.
// ---------------------------------------------------------------------------
#define K2_TILE 2048
#define K2_SEGS 256
#define D1_REPS 3

__global__ void __launch_bounds__(K2_SEGS)
seg_lse_dbuf3(const float* __restrict__ x,
              const int* __restrict__ offs,
              float* __restrict__ out,
              int E, int S) {
    __shared__ float lds[2][K2_TILE];
    const int tid = threadIdx.x;
    const int s0  = blockIdx.x * K2_SEGS;
    const int send = min(s0 + K2_SEGS, S);
    const int sid  = s0 + tid;

    int b = 0, e = 0;
    if (sid < S) { b = offs[sid]; e = offs[sid + 1]; }
    const int block_beg = offs[s0];
    const int block_end = offs[send];
    const int li0 = tid * 4;
    const int li1 = (K2_SEGS + tid) * 4;

    float total = 0.0f;
    for (int rep = 0; rep < D1_REPS; ++rep) {
        float sum = 0.0f;
        // opaque seed + memory clobber: reps cannot be CSE'd or collapsed
        asm volatile("" : "+v"(sum) :: "memory");

        int t0 = block_beg & ~3;
        float4 r0, r1;
        {
            int g0 = t0 + li0, g1 = t0 + li1;
            if (g0 < E) r0 = *reinterpret_cast<const float4*>(x + g0);
            if (g1 < E) r1 = *reinterpret_cast<const float4*>(x + g1);
        }
        int cur = 0;
        while (t0 < block_end) {
            {
                int g0 = t0 + li0, g1 = t0 + li1;
                if (g0 < E) {
                    lds[cur][li0 + 0] = __expf(r0.x);
                    lds[cur][li0 + 1] = __expf(r0.y);
                    lds[cur][li0 + 2] = __expf(r0.z);
                    lds[cur][li0 + 3] = __expf(r0.w);
                }
                if (g1 < E) {
                    lds[cur][li1 + 0] = __expf(r1.x);
                    lds[cur][li1 + 1] = __expf(r1.y);
                    lds[cur][li1 + 2] = __expf(r1.z);
                    lds[cur][li1 + 3] = __expf(r1.w);
                }
            }
            const int tn = t0 + K2_TILE;
            if (tn < block_end) {
                int g0 = tn + li0, g1 = tn + li1;
                if (g0 < E) r0 = *reinterpret_cast<const float4*>(x + g0);
                if (g1 < E) r1 = *reinterpret_cast<const float4*>(x + g1);
            }
            __syncthreads();

            const int lo = max(b, t0), hi = min(e, tn);
            const float* __restrict__ buf = lds[cur];
            float a0 = 0.f, a1 = 0.f, a2 = 0.f, a3 = 0.f;
            int i = lo;
            while (i < hi && (i & 3)) { a0 += buf[i - t0]; ++i; }
            for (; i + 4 <= hi; i += 4) {
                float4 v = *reinterpret_cast<const float4*>(buf + (i - t0));
                a0 += v.x; a1 += v.y; a2 += v.z; a3 += v.w;
            }
            for (; i < hi; ++i) a0 += buf[i - t0];
            sum += (a0 + a1) + (a2 + a3);

            __syncthreads();
            t0 = tn;
            cur ^= 1;
        }
        total += sum;
    }
    // total = 3*sum (up to 1 ulp); /3 restores sum with ~1e-7 rel error
    if (sid < S) out[sid] = __logf(total * (1.0f / D1_REPS));
}

// ---------------------------------------------------------------------------
// D2: pure linear float4 read of x, same grid shape as K2, 5 reps, sink to ws.
// ---------------------------------------------------------------------------
#define LR_REPS 5

__global__ void __launch_bounds__(256)
lin_read5(const float* __restrict__ x, float* __restrict__ sink, int E) {
    const int tid  = threadIdx.x;
    const int blk  = blockIdx.x;
    const int base = blk * 8192;          // E / 4096 floats per block
    float acc = 0.0f;
    for (int rep = 0; rep < LR_REPS; ++rep) {
        float a0 = 0.f, a1 = 0.f, a2 = 0.f, a3 = 0.f;
        asm volatile("" : "+v"(a0) :: "memory");
        #pragma unroll
        for (int j = 0; j < 8; ++j) {     // 8 independent b128 loads in flight
            int g = base + j * 1024 + tid * 4;
            float4 v = *reinterpret_cast<const float4*>(x + g);
            a0 += v.x; a1 += v.y; a2 += v.z; a3 += v.w;
        }
        acc += (a0 + a1) + (a2 + a3);
    }
    sink[blk * 256 + tid] = acc;          // offs region; dead after D1
}

extern "C" void kernel_launch(void* const* d_in, const int* in_sizes, int n_in,
                              void* d_out, int out_size, void* d_ws, size_t ws_size,
                              hipStream_t stream) {
    const float* x      = (const float*)d_in[0];
    const int*   ix_out = (const int*)d_in[1];
    // d_in[2] (ix_in) unused in forward.

    const int E = in_sizes[0];      // 33_554_432
    const int S = out_size;         // 1_048_576

    int* offs  = (int*)d_ws;        // S+1 ints; fully rewritten every call by K1
    float* out = (float*)d_out;

    {
        int threads = (E + 3) / 4;
        int block = 256;
        int grid = (threads + block - 1) / block;
        seg_offsets_kernel<<<grid, block, 0, stream>>>(ix_out, offs, E, S);
    }
    {
        int grid = (S + K2_SEGS - 1) / K2_SEGS;   // 4096
        seg_lse_dbuf3<<<grid, K2_SEGS, 0, stream>>>(x, offs, out, E, S);
    }
    {
        // diagnostic: overwrites the (now dead) offs region; K1 rewrites it
        // from scratch next call, so no cross-call state dependence.
        lin_read5<<<4096, 256, 0, stream>>>(x, (float*)d_ws, E);
    }
}

// Round 13
// 59.411 us; speedup vs baseline: 2.2814x; 2.2814x over previous
//
#include <hip/hip_runtime.h>
#include <hip/hip_bf16.h>
#include <math.h>

// Segmented logsumexp over sorted keys.
// out[s] = log( sum_{i: ix_out[i]==s} exp(x[i]) )  (== log(sum exp(x-mx))+mx exactly;
// x ~ N(0,1) so no overflow; empty segment -> log(0) = -inf, matching reference).
//
// Round-12 diagnostic: pure-read path >=7 TB/s, staging+reduce machinery =
// 1.7x pure read (VALUBusy 40%). This round deletes the machinery: K2 uses
// global_load_lds DMA staging (no VGPR round-trip, no expf-at-stage, no
// ds_writes) in a wave-private zero-barrier schedule (wave-local vmcnt wait
// only), 10 KB in flight per wave. K1 unchanged (at its traffic floor).

// ---------------------------------------------------------------------------
// K1: offs[s] = first edge index with key >= s, for s in [0, S]; offs[S] = E.
// ---------------------------------------------------------------------------
__global__ void seg_offsets_kernel(const int* __restrict__ keys,
                                   int* __restrict__ offs,
                                   int E, int S) {
    int t = blockIdx.x * blockDim.x + threadIdx.x;
    int i0 = t * 4;
    if (i0 >= E) return;

    int4 k4 = reinterpret_cast<const int4*>(keys)[t];
    int prev = (i0 == 0) ? -1 : keys[i0 - 1];

    int ks[4] = {k4.x, k4.y, k4.z, k4.w};
    #pragma unroll
    for (int j = 0; j < 4; ++j) {
        int k = ks[j];
        for (int s = prev + 1; s <= k; ++s) offs[s] = i0 + j;
        prev = k;
    }
    if (i0 + 4 == E) {
        for (int s = prev + 1; s <= S; ++s) offs[s] = E;
    }
}

// ---------------------------------------------------------------------------
// K2: wave-private global_load_lds staging + in-LDS segmented reduce.
// Wave w owns segments [s0, s0+64); lane l reduces segment s0+l.
// ---------------------------------------------------------------------------
#define K2_WAVES 4
#define K2_TPB   256
#define WBUF     2432   // floats per wave buffer (9.5 KB); range ~Poisson(2048),
                        // 2432 = mu + 8.5 sigma; uniform fallback covers beyond.

typedef __attribute__((address_space(3))) void        lds_void_t;
typedef const __attribute__((address_space(1))) void  g_void_t;

__global__ void __launch_bounds__(K2_TPB)
seg_lse_gll(const float* __restrict__ x,
            const int* __restrict__ offs,
            float* __restrict__ out,
            int E) {
    __shared__ float lds[K2_WAVES][WBUF];
    const int lane = threadIdx.x & 63;
    const int w    = threadIdx.x >> 6;
    const int s0   = (blockIdx.x * K2_WAVES + w) * 64;
    const int sid  = s0 + lane;                 // S % 256 == 0 -> in range

    const int b  = offs[sid];
    const int e  = offs[sid + 1];
    const int rb = __shfl(b, 0, 64) & ~3;       // wave range start, 16B-aligned
    const int re = __shfl(e, 63, 64);           // wave range end
    const int len = re - rb;                    // wave-uniform

    float* buf = &lds[w][0];
    float a0 = 0.f, a1 = 0.f, a2 = 0.f, a3 = 0.f;

    if (len <= WBUF) {
        // DMA the wave's whole contiguous range into its private LDS slice.
        // Each instr: 64 lanes x 16 B = 1 KB; dest = uniform base + lane*16
        // (linear layout matches exactly); src per-lane, 16B-aligned; clamped
        // sources only feed slots beyond len, which are never read.
        for (int u = 0; u * 256 < len; ++u) {
            const float* src = x + min(rb + u * 256 + lane * 4, E - 4);
            __builtin_amdgcn_global_load_lds((g_void_t*)src,
                                             (lds_void_t*)(buf + u * 256),
                                             16, 0, 0);
        }
        asm volatile("s_waitcnt vmcnt(0)" ::: "memory");  // wave-local; no barrier
        __builtin_amdgcn_sched_barrier(0);

        // per-lane reduce of [b, e) from LDS, exp folded in, branchless masks
        for (int i = (b & ~3); i < e; i += 4) {
            float4 v = *reinterpret_cast<const float4*>(buf + (i - rb));
            a0 += (i >= b)                  ? __expf(v.x) : 0.0f;  // i < e by loop
            a1 += (i + 1 >= b && i + 1 < e) ? __expf(v.y) : 0.0f;
            a2 += (i + 2 >= b && i + 2 < e) ? __expf(v.z) : 0.0f;
            a3 += (i + 3 < e)               ? __expf(v.w) : 0.0f;  // i+3 >= b always
        }
    } else {
        // pathological wave range (p ~ 1e-13 for this data): direct global,
        // wave-uniform branch, correctness-only.
        for (int i = b; i < e; ++i) a0 += __expf(x[i]);
    }

    const float sum = (a0 + a1) + (a2 + a3);    // fixed combine tree
    out[sid] = __logf(sum);   // empty segment: log(0) = -inf, matches reference
}

extern "C" void kernel_launch(void* const* d_in, const int* in_sizes, int n_in,
                              void* d_out, int out_size, void* d_ws, size_t ws_size,
                              hipStream_t stream) {
    const float* x      = (const float*)d_in[0];
    const int*   ix_out = (const int*)d_in[1];
    // d_in[2] (ix_in) unused in forward.

    const int E = in_sizes[0];      // 33_554_432
    const int S = out_size;         // 1_048_576 (divisible by 256)

    int* offs  = (int*)d_ws;        // S+1 ints (~4 MB), fully rewritten each call
    float* out = (float*)d_out;

    {
        int threads = (E + 3) / 4;
        int block = 256;
        int grid = (threads + block - 1) / block;
        seg_offsets_kernel<<<grid, block, 0, stream>>>(ix_out, offs, E, S);
    }
    {
        int grid = S / (K2_WAVES * 64);   // 4096 blocks, 64 segments per wave
        seg_lse_gll<<<grid, K2_TPB, 0, stream>>>(x, offs, out, E);
    }
}